// Round 4
// baseline (631.624 us; speedup 1.0000x reference)
//
#include <hip/hip_runtime.h>
#include <hip/hip_bf16.h>
#include <stdint.h>

#define IN_DIM 384
#define HID 64
#define C1 256   // 4 heads * 64
#define C2 128   // 2 heads * 64

typedef unsigned int uint32;
typedef __bf16 bf16x8 __attribute__((ext_vector_type(8)));
typedef float f32x4 __attribute__((ext_vector_type(4)));

static __device__ __forceinline__ float bf2f(unsigned short u){
    return __uint_as_float(((uint32)u) << 16);
}
static __device__ __forceinline__ unsigned short f2bf(float x){
    uint32 u = __float_as_uint(x);
    return (unsigned short)((u + 0x7FFFu + ((u >> 16) & 1u)) >> 16);
}
static __device__ __forceinline__ uint32 pack2(float a, float b){
    return (uint32)f2bf(a) | ((uint32)f2bf(b) << 16);
}

// ---------------- CSR build ----------------
__global__ void k_zero(int* deg, int* cur, int N){
    int i = blockIdx.x*256 + threadIdx.x;
    if (i < N){ deg[i] = 0; cur[i] = 0; }
}
__global__ void k_hist(const int* __restrict__ ei, int* deg, int E){
    int i = blockIdx.x*256 + threadIdx.x;
    if (i < E) atomicAdd(&deg[ei[E + i]], 1);
}
__global__ void k_scan1(const int* __restrict__ deg, int* rowptr, int* part, int N){
    __shared__ int s[256];
    int tid = threadIdx.x;
    int i = blockIdx.x*256 + tid;
    int v = (i < N) ? deg[i] : 0;
    s[tid] = v; __syncthreads();
    for (int off = 1; off < 256; off <<= 1){
        int t = (tid >= off) ? s[tid - off] : 0;
        __syncthreads();
        s[tid] += t;
        __syncthreads();
    }
    if (i < N) rowptr[i] = s[tid] - v;
    if (tid == 255) part[blockIdx.x] = s[tid];
}
__global__ void k_scan2(int* part, int nb){
    __shared__ int s[512];
    int tid = threadIdx.x;
    int v = (tid < nb) ? part[tid] : 0;
    s[tid] = v; __syncthreads();
    for (int off = 1; off < 512; off <<= 1){
        int t = (tid >= off) ? s[tid - off] : 0;
        __syncthreads();
        s[tid] += t;
        __syncthreads();
    }
    if (tid < nb) part[tid] = s[tid] - v;
}
__global__ void k_scan3(int* rowptr, const int* __restrict__ part, int N, int E){
    int i = blockIdx.x*256 + threadIdx.x;
    if (i < N) rowptr[i] += part[blockIdx.x];
    if (i == 0) rowptr[N] = E;
}
__global__ void k_scatter(const int* __restrict__ ei, const int* __restrict__ rowptr,
                          int* cur, int* colx, int E){
    int i = blockIdx.x*256 + threadIdx.x;
    if (i < E){
        int d = ei[E + i];
        int pos = atomicAdd(&cur[d], 1);
        colx[rowptr[d] + pos] = ei[i];
    }
}

// ---------------- weight pre-swizzle: contiguous-k fragment order ----------------
// Wf[unit = s*ntiles+ct][lane l][j] = W[k = s*32 + 8*(l>>4) + j][ct*16 + (l&15)]
__global__ __launch_bounds__(256) void k_cvtW(const float* __restrict__ W,
        unsigned short* __restrict__ Wf, int ncol, int ntiles, int nunits){
    int unit = blockIdx.x*4 + (threadIdx.x >> 6);
    if (unit >= nunits) return;
    int l = threadIdx.x & 63;
    int s = unit / ntiles, ct = unit % ntiles;
    int col = ct*16 + (l & 15);
    int g = l >> 4;
    unsigned short o[8];
    #pragma unroll
    for (int j = 0; j < 8; j++){
        int k = s*32 + g*8 + j;
        o[j] = f2bf(W[(size_t)k*ncol + col]);
    }
    ushort4* dst = (ushort4*)&Wf[((size_t)unit*64 + l)*8];
    dst[0] = make_ushort4(o[0], o[1], o[2], o[3]);
    dst[1] = make_ushort4(o[4], o[5], o[6], o[7]);
}

// ---------------- constant precompute: pad bias, emotion gate, aw1 transpose --------
__global__ __launch_bounds__(256) void k_prep(const float* __restrict__ W1,
        const float* __restrict__ pad, const float* __restrict__ gw, const float* __restrict__ gb,
        const float* __restrict__ aw1,
        float* __restrict__ c1v, float* __restrict__ gate, float* __restrict__ aw1t){
    int tid = threadIdx.x;
    c1v[tid] = pad[0]*W1[(size_t)(IN_DIM+0)*C1 + tid]
             + pad[1]*W1[(size_t)(IN_DIM+1)*C1 + tid]
             + pad[2]*W1[(size_t)(IN_DIM+2)*C1 + tid];
    if (tid < HID){
        float g = pad[0]*gw[0*HID + tid] + pad[1]*gw[1*HID + tid] + pad[2]*gw[2*HID + tid] + gb[tid];
        gate[tid] = 1.f/(1.f + __expf(-g));
    }
    for (int i = tid; i < C2*HID; i += 256){
        int c = i >> 6, l = i & 63;
        aw1t[l*C2 + c] = aw1[i];
    }
}

// ---------------- GEMM1 (MFMA): h1 = [x|pad]@W1 + fused al1 epilogue ----------------
__global__ __launch_bounds__(256) void k_gemm1_mfma(const float* __restrict__ x,
        const unsigned short* __restrict__ Wf, const float* __restrict__ c1v,
        const float* __restrict__ as1, const float* __restrict__ ad1,
        unsigned short* __restrict__ h1, float* __restrict__ als, float* __restrict__ ald, int N)
{
    __shared__ unsigned short Af[2][8*64*8];   // 2 x 8KB
    const int tid = threadIdx.x;
    const int l   = tid & 63;
    const int w   = tid >> 6;
    const int n0  = blockIdx.x * 128;

    const int srow = tid & 127;
    const int jh   = tid >> 7;
    const int srt  = srow >> 4, srr = srow & 15;
    const int d0   = (srt*64 + (jh*2+0)*16 + srr)*8;
    const int d1   = (srt*64 + (jh*2+1)*16 + srr)*8;
    int crow = n0 + srow; if (crow > N-1) crow = N-1;
    const float* xrow = x + (size_t)crow*IN_DIM + jh*16;

    f32x4 acc[4][8];
    #pragma unroll
    for (int i = 0; i < 4; i++)
        #pragma unroll
        for (int rt = 0; rt < 8; rt++)
            acc[i][rt] = (f32x4){0.f, 0.f, 0.f, 0.f};

    float4 ra, rb, rc, rd;
    uint4 wcur[4], wnxt[4];

    ra = *(const float4*)(xrow + 0); rb = *(const float4*)(xrow + 4);
    rc = *(const float4*)(xrow + 8); rd = *(const float4*)(xrow + 12);
    {
        uint4 u0, u1;
        u0.x = pack2(ra.x, ra.y); u0.y = pack2(ra.z, ra.w);
        u0.z = pack2(rb.x, rb.y); u0.w = pack2(rb.z, rb.w);
        u1.x = pack2(rc.x, rc.y); u1.y = pack2(rc.z, rc.w);
        u1.z = pack2(rd.x, rd.y); u1.w = pack2(rd.z, rd.w);
        *(uint4*)&Af[0][d0] = u0;
        *(uint4*)&Af[0][d1] = u1;
    }
    {
        const unsigned short* p = Wf + ((size_t)(w*4)*64 + l)*8;
        #pragma unroll
        for (int i = 0; i < 4; i++) wcur[i] = *(const uint4*)(p + (size_t)i*512);
    }
    __syncthreads();

    for (int s = 0; s < 12; ++s){
        if (s < 11){
            const float* src = xrow + (s+1)*32;
            ra = *(const float4*)(src + 0); rb = *(const float4*)(src + 4);
            rc = *(const float4*)(src + 8); rd = *(const float4*)(src + 12);
            const unsigned short* p = Wf + ((size_t)((s+1)*16 + w*4)*64 + l)*8;
            #pragma unroll
            for (int i = 0; i < 4; i++) wnxt[i] = *(const uint4*)(p + (size_t)i*512);
        }
        bf16x8 af[8];
        #pragma unroll
        for (int rt = 0; rt < 8; rt++)
            af[rt] = __builtin_bit_cast(bf16x8, *(const uint4*)&Af[s&1][(rt*64 + l)*8]);
        #pragma unroll
        for (int i = 0; i < 4; i++){
            bf16x8 bw = __builtin_bit_cast(bf16x8, wcur[i]);
            #pragma unroll
            for (int rt = 0; rt < 8; rt++)
                acc[i][rt] = __builtin_amdgcn_mfma_f32_16x16x32_bf16(bw, af[rt], acc[i][rt], 0, 0, 0);
        }
        if (s < 11){
            uint4 u0, u1;
            u0.x = pack2(ra.x, ra.y); u0.y = pack2(ra.z, ra.w);
            u0.z = pack2(rb.x, rb.y); u0.w = pack2(rb.z, rb.w);
            u1.x = pack2(rc.x, rc.y); u1.y = pack2(rc.z, rc.w);
            u1.z = pack2(rd.x, rd.y); u1.w = pack2(rd.z, rd.w);
            *(uint4*)&Af[(s+1)&1][d0] = u0;
            *(uint4*)&Af[(s+1)&1][d1] = u1;
            __syncthreads();
            #pragma unroll
            for (int i = 0; i < 4; i++) wcur[i] = wnxt[i];
        }
    }

    const int g = l >> 4;
    float4 cvv[4], av[4], dv[4];
    #pragma unroll
    for (int i = 0; i < 4; i++){
        int cl = i*16 + g*4;
        cvv[i] = *(const float4*)&c1v[w*64 + cl];
        av[i]  = *(const float4*)&as1[w*64 + cl];
        dv[i]  = *(const float4*)&ad1[w*64 + cl];
    }
    #pragma unroll
    for (int rt = 0; rt < 8; rt++){
        int node = n0 + rt*16 + (l & 15);
        bool ok = node < N;
        float ps = 0.f, pd = 0.f;
        #pragma unroll
        for (int i = 0; i < 4; i++){
            float h0 = acc[i][rt][0] + cvv[i].x;
            float h1v = acc[i][rt][1] + cvv[i].y;
            float h2v = acc[i][rt][2] + cvv[i].z;
            float h3v = acc[i][rt][3] + cvv[i].w;
            ps += h0*av[i].x + h1v*av[i].y + h2v*av[i].z + h3v*av[i].w;
            pd += h0*dv[i].x + h1v*dv[i].y + h2v*dv[i].z + h3v*dv[i].w;
            if (ok){
                ushort4 o = make_ushort4(f2bf(h0), f2bf(h1v), f2bf(h2v), f2bf(h3v));
                *(ushort4*)&h1[(size_t)node*C1 + w*64 + i*16 + g*4] = o;
            }
        }
        ps += __shfl_xor(ps, 16, 64); ps += __shfl_xor(ps, 32, 64);
        pd += __shfl_xor(pd, 16, 64); pd += __shfl_xor(pd, 32, 64);
        if (ok && g == 0){
            als[(size_t)node*4 + w] = ps;
            ald[(size_t)node*4 + w] = pd;
        }
    }
}

// ---------------- GEMM2 (MFMA): h2 = x2 @ W2 + fused al2 epilogue ----------------
__global__ __launch_bounds__(256) void k_gemm2_mfma(const unsigned short* __restrict__ x2,
        const unsigned short* __restrict__ Wf,
        const float* __restrict__ as2, const float* __restrict__ ad2,
        unsigned short* __restrict__ h2, float* __restrict__ als, float* __restrict__ ald, int N)
{
    __shared__ unsigned short Af[2][8*64*8];
    const int tid = threadIdx.x;
    const int l   = tid & 63;
    const int w   = tid >> 6;
    const int wr  = w >> 1, wc = w & 1;
    const int n0  = blockIdx.x * 128;

    const int srow = tid >> 1;
    const int half = tid & 1;
    const int srt  = srow >> 4, srr = srow & 15;
    const int d0   = (srt*64 + (half*2+0)*16 + srr)*8;
    const int d1   = d0 + 128;
    int crow = n0 + srow; if (crow > N-1) crow = N-1;
    const unsigned short* xrow = x2 + (size_t)crow*C1 + half*16;

    f32x4 acc[4][4];
    #pragma unroll
    for (int i = 0; i < 4; i++)
        #pragma unroll
        for (int rt = 0; rt < 4; rt++)
            acc[i][rt] = (f32x4){0.f, 0.f, 0.f, 0.f};

    uint4 p0, p1, wcur[4], wnxt[4];
    p0 = *(const uint4*)(xrow + 0);
    p1 = *(const uint4*)(xrow + 8);
    *(uint4*)&Af[0][d0] = p0;
    *(uint4*)&Af[0][d1] = p1;
    {
        const unsigned short* p = Wf + ((size_t)(wc*4)*64 + l)*8;
        #pragma unroll
        for (int i = 0; i < 4; i++) wcur[i] = *(const uint4*)(p + (size_t)i*512);
    }
    __syncthreads();

    for (int s = 0; s < 8; ++s){
        if (s < 7){
            p0 = *(const uint4*)(xrow + (s+1)*32);
            p1 = *(const uint4*)(xrow + (s+1)*32 + 8);
            const unsigned short* p = Wf + ((size_t)((s+1)*8 + wc*4)*64 + l)*8;
            #pragma unroll
            for (int i = 0; i < 4; i++) wnxt[i] = *(const uint4*)(p + (size_t)i*512);
        }
        bf16x8 af[4];
        #pragma unroll
        for (int rt = 0; rt < 4; rt++)
            af[rt] = __builtin_bit_cast(bf16x8, *(const uint4*)&Af[s&1][((wr*4 + rt)*64 + l)*8]);
        #pragma unroll
        for (int i = 0; i < 4; i++){
            bf16x8 bw = __builtin_bit_cast(bf16x8, wcur[i]);
            #pragma unroll
            for (int rt = 0; rt < 4; rt++)
                acc[i][rt] = __builtin_amdgcn_mfma_f32_16x16x32_bf16(bw, af[rt], acc[i][rt], 0, 0, 0);
        }
        if (s < 7){
            *(uint4*)&Af[(s+1)&1][d0] = p0;
            *(uint4*)&Af[(s+1)&1][d1] = p1;
            __syncthreads();
            #pragma unroll
            for (int i = 0; i < 4; i++) wcur[i] = wnxt[i];
        }
    }

    const int g = l >> 4;
    float4 av[4], dv[4];
    #pragma unroll
    for (int i = 0; i < 4; i++){
        int cl = i*16 + g*4;
        av[i] = *(const float4*)&as2[wc*64 + cl];
        dv[i] = *(const float4*)&ad2[wc*64 + cl];
    }
    #pragma unroll
    for (int rt = 0; rt < 4; rt++){
        int node = n0 + wr*64 + rt*16 + (l & 15);
        bool ok = node < N;
        float ps = 0.f, pd = 0.f;
        #pragma unroll
        for (int i = 0; i < 4; i++){
            float h0 = acc[i][rt][0], h1v = acc[i][rt][1];
            float h2v = acc[i][rt][2], h3v = acc[i][rt][3];
            ps += h0*av[i].x + h1v*av[i].y + h2v*av[i].z + h3v*av[i].w;
            pd += h0*dv[i].x + h1v*dv[i].y + h2v*dv[i].z + h3v*dv[i].w;
            if (ok){
                ushort4 o = make_ushort4(f2bf(h0), f2bf(h1v), f2bf(h2v), f2bf(h3v));
                *(ushort4*)&h2[(size_t)node*C2 + wc*64 + i*16 + g*4] = o;
            }
        }
        ps += __shfl_xor(ps, 16, 64); ps += __shfl_xor(ps, 32, 64);
        pd += __shfl_xor(pd, 16, 64); pd += __shfl_xor(pd, 32, 64);
        if (ok && g == 0){
            als[(size_t)node*2 + wc] = ps;
            ald[(size_t)node*2 + wc] = pd;
        }
    }
}

// ---------------- per-node TWO-PASS softmax aggregation (one wave per node) ----------
// pass 1: max of logits (4-wide unroll, clamped idx - idempotent for max)
// pass 2: independent exp + gather + FMA (4 gathers in flight)
template<int HEADS, int CPL, int LAYER>
__global__ __launch_bounds__(256) void k_agg(const unsigned short* __restrict__ hlin,
        const float* __restrict__ als, const float* __restrict__ ald,
        const int* __restrict__ rowptr, const int* __restrict__ colx,
        const float* __restrict__ bias,
        const float* __restrict__ gate, const float* __restrict__ aw1t,
        const float* __restrict__ ab1, const float* __restrict__ aw2, const float* __restrict__ ab2,
        unsigned short* __restrict__ out_bf, float* __restrict__ out_f,
        float* __restrict__ attn, int N)
{
    constexpr int C = HEADS*64;
    constexpr uint32 RB = C*2;               // bf16 row bytes
    __shared__ float hs[4][C2];
    int lane = threadIdx.x & 63, wid = threadIdx.x >> 6;
    int n = blockIdx.x*4 + wid;
    if (n >= N) return;
    const int c0 = lane*CPL;
    const int head = c0 >> 6;
    const int base = rowptr[n];
    const int cnt  = rowptr[n+1] - base;
    const float* alsh = als + head;
    const char* hbase = (const char*)hlin + (uint32)c0*2;

    const float myald = ald[(size_t)n*HEADS + head];
    float e_self = alsh[(size_t)n*HEADS] + myald;
    e_self = fmaxf(e_self, 0.2f*e_self);

    // ---- pass 1: global max ----
    float m = e_self;
    for (int i = 0; i < cnt; i += 4){
        int sk[4];
        #pragma unroll
        for (int k = 0; k < 4; k++){
            int ii = i + k; if (ii > cnt-1) ii = cnt-1;
            sk[k] = colx[base + ii];
        }
        float ek[4];
        #pragma unroll
        for (int k = 0; k < 4; k++) ek[k] = alsh[(size_t)sk[k]*HEADS];
        #pragma unroll
        for (int k = 0; k < 4; k++){
            float e = ek[k] + myald;
            e = fmaxf(e, 0.2f*e);
            m = fmaxf(m, e);
        }
    }

    // ---- pass 2: independent exp + gather-accumulate ----
    float den = __expf(e_self - m);
    float acc[CPL];
    {
        if constexpr (CPL == 4){
            ushort4 v = *(const ushort4*)(hbase + (uint32)n*RB);
            acc[0] = den*bf2f(v.x); acc[1] = den*bf2f(v.y);
            acc[2] = den*bf2f(v.z); acc[3] = den*bf2f(v.w);
        } else {
            uint32 v = *(const uint32*)(hbase + (uint32)n*RB);
            acc[0] = den*bf2f((unsigned short)(v & 0xffff));
            acc[1] = den*bf2f((unsigned short)(v >> 16));
        }
    }
    for (int i = 0; i < cnt; i += 4){
        int sk[4];
        #pragma unroll
        for (int k = 0; k < 4; k++){
            int ii = i + k; if (ii > cnt-1) ii = cnt-1;
            sk[k] = colx[base + ii];
        }
        ushort4 h4[4]; uint32 h2v[4];
        #pragma unroll
        for (int k = 0; k < 4; k++){
            if constexpr (CPL == 4) h4[k]  = *(const ushort4*)(hbase + (uint32)sk[k]*RB);
            else                    h2v[k] = *(const uint32*)(hbase + (uint32)sk[k]*RB);
        }
        float ek[4];
        #pragma unroll
        for (int k = 0; k < 4; k++) ek[k] = alsh[(size_t)sk[k]*HEADS];
        float pk[4];
        #pragma unroll
        for (int k = 0; k < 4; k++){
            float e = ek[k] + myald;
            e = fmaxf(e, 0.2f*e);
            float p = __expf(e - m);
            pk[k] = (i + k < cnt) ? p : 0.f;
        }
        den += (pk[0] + pk[1]) + (pk[2] + pk[3]);
        #pragma unroll
        for (int k = 0; k < 4; k++){
            if constexpr (CPL == 4){
                acc[0] += pk[k]*bf2f(h4[k].x);
                acc[1] += pk[k]*bf2f(h4[k].y);
                acc[2] += pk[k]*bf2f(h4[k].z);
                acc[3] += pk[k]*bf2f(h4[k].w);
            } else {
                acc[0] += pk[k]*bf2f((unsigned short)(h2v[k] & 0xffff));
                acc[1] += pk[k]*bf2f((unsigned short)(h2v[k] >> 16));
            }
        }
    }

    float inv = 1.f/(den + 1e-16f);
    if constexpr (LAYER == 1){
        unsigned short o[CPL];
        #pragma unroll
        for (int j = 0; j < CPL; j++){
            float r = acc[j]*inv + bias[c0 + j];
            r = (r > 0.f) ? r : (__expf(r) - 1.f);   // elu
            o[j] = f2bf(r);
        }
        if constexpr (CPL == 4){
            ushort4 ov; ov.x = o[0]; ov.y = o[1]; ov.z = o[2]; ov.w = o[3];
            *(ushort4*)&out_bf[(size_t)n*C + c0] = ov;
        }
    } else {
        #pragma unroll
        for (int j = 0; j < CPL; j++){
            float r = acc[j]*inv + bias[c0 + j];
            r = (r > 0.f) ? r : (__expf(r) - 1.f);   // elu
            float o = r*gate[(c0 + j) & 63];
            out_f[(size_t)n*C + c0 + j] = o;
            hs[wid][c0 + j] = o;
        }
        // fused attention-score MLP (wave-local; aw1 pre-transposed to [64][128])
        float a = ab1[lane];
        const float* awrow = aw1t + lane*C2;
        #pragma unroll 8
        for (int c = 0; c < C2; c += 4){
            float4 hv4 = *(const float4*)&hs[wid][c];
            float4 w4  = *(const float4*)&awrow[c];
            a += hv4.x*w4.x + hv4.y*w4.y + hv4.z*w4.z + hv4.w*w4.w;
        }
        a = fmaxf(a, 0.f);
        float part = a*aw2[lane];
        #pragma unroll
        for (int mm = 32; mm >= 1; mm >>= 1) part += __shfl_xor(part, mm, 64);
        if (lane == 0) attn[n] = 1.f/(1.f + __expf(-(part + ab2[0])));
    }
}

extern "C" void kernel_launch(void* const* d_in, const int* in_sizes, int n_in,
                              void* d_out, int out_size, void* d_ws, size_t ws_size,
                              hipStream_t stream)
{
    const float* x    = (const float*)d_in[0];
    const int*   ei   = (const int*)  d_in[1];
    const float* pad  = (const float*)d_in[2];
    const float* W1   = (const float*)d_in[3];
    const float* as1  = (const float*)d_in[4];
    const float* ad1  = (const float*)d_in[5];
    const float* b1   = (const float*)d_in[6];
    const float* W2   = (const float*)d_in[7];
    const float* as2  = (const float*)d_in[8];
    const float* ad2  = (const float*)d_in[9];
    const float* b2   = (const float*)d_in[10];
    const float* aw1  = (const float*)d_in[11];
    const float* ab1  = (const float*)d_in[12];
    const float* aw2  = (const float*)d_in[13];
    const float* ab2  = (const float*)d_in[14];
    const float* gw   = (const float*)d_in[15];
    const float* gb   = (const float*)d_in[16];

    const int N = in_sizes[0] / IN_DIM;
    const int E = in_sizes[1] / 2;

    float* outh    = (float*)d_out;
    float* outattn = outh + (size_t)N*C2;

    char* w = (char*)d_ws;
    auto alloc = [&](size_t bytes)->char*{
        char* p = w;
        w += (bytes + 255) & ~(size_t)255;
        return p;
    };
    unsigned short* h1  = (unsigned short*)alloc((size_t)N*C1*2);
    unsigned short* x2  = (unsigned short*)alloc((size_t)N*C1*2);
    unsigned short* h2  = (unsigned short*)alloc((size_t)N*C2*2);
    float* als1 = (float*)alloc((size_t)N*4*4);
    float* ald1 = (float*)alloc((size_t)N*4*4);
    float* als2 = (float*)alloc((size_t)N*2*4);
    float* ald2 = (float*)alloc((size_t)N*2*4);
    int* deg    = (int*)alloc((size_t)N*4);
    int* cur    = (int*)alloc((size_t)N*4);
    int* rowptr = (int*)alloc((size_t)(N+1)*4);
    int* colx   = (int*)alloc((size_t)E*4);
    int* part   = (int*)alloc(512*4);
    unsigned short* Wf1 = (unsigned short*)alloc((size_t)12*16*64*8*2);
    unsigned short* Wf2 = (unsigned short*)alloc((size_t)8*8*64*8*2);
    float* c1v  = (float*)alloc(C1*4);
    float* gate = (float*)alloc(HID*4);
    float* aw1t = (float*)alloc((size_t)C2*HID*4);

    const int nbN = (N + 255)/256;
    const int nbE = (E + 255)/256;
    const int nbW = (N + 3)/4;        // wave-per-node kernels
    const int nbG = (N + 127)/128;    // gemm row blocks

    // weight swizzles + constants (independent of CSR)
    k_cvtW <<<(192+3)/4, 256, 0, stream>>>(W1, Wf1, C1, 16, 192);
    k_cvtW <<<(64+3)/4,  256, 0, stream>>>(W2, Wf2, C2, 8, 64);
    k_prep <<<1, 256, 0, stream>>>(W1, pad, gw, gb, aw1, c1v, gate, aw1t);

    // CSR by destination
    k_zero   <<<nbN, 256, 0, stream>>>(deg, cur, N);
    k_hist   <<<nbE, 256, 0, stream>>>(ei, deg, E);
    k_scan1  <<<nbN, 256, 0, stream>>>(deg, rowptr, part, N);
    k_scan2  <<<1, 512, 0, stream>>>(part, nbN);
    k_scan3  <<<nbN, 256, 0, stream>>>(rowptr, part, N, E);
    k_scatter<<<nbE, 256, 0, stream>>>(ei, rowptr, cur, colx, E);

    k_gemm1_mfma<<<nbG, 256, 0, stream>>>(x, Wf1, c1v, as1, ad1, h1, als1, ald1, N);
    k_agg<4,4,1><<<nbW, 256, 0, stream>>>(h1, als1, ald1, rowptr, colx, b1,
                                          nullptr, nullptr, nullptr, nullptr, nullptr,
                                          x2, nullptr, nullptr, N);

    k_gemm2_mfma<<<nbG, 256, 0, stream>>>(x2, Wf2, as2, ad2, h2, als2, ald2, N);
    k_agg<2,2,2><<<nbW, 256, 0, stream>>>(h2, als2, ald2, rowptr, colx, b2,
                                          gate, aw1t, ab1, aw2, ab2,
                                          nullptr, outh, outattn, N);
}